// Round 11
// baseline (496.277 us; speedup 1.0000x reference)
//
#include <hip/hip_runtime.h>
#include <hip/hip_cooperative_groups.h>

namespace cg = cooperative_groups;

#define DIM 128
#define BN_EPS_F 1e-5f
#define NSLICE 16   // stat slices: spreads atomic contention; preamble reduces them
#define MAXN 10240  // LDS histogram capacity (n = 10000)
#define CHUNKS 256  // edge chunks == blocks in chunkhist/scatter
#define SPL (2 * NSLICE * DIM)  // stats floats per layer (sums + squares)

typedef unsigned int u32;
typedef unsigned short u16;

__device__ __forceinline__ float bflo(u32 w) {
    union { u32 u; float f; } c; c.u = w << 16; return c.f;
}
__device__ __forceinline__ float bfhi(u32 w) {
    union { u32 u; float f; } c; c.u = w & 0xffff0000u; return c.f;
}
// pack two floats to bf16x2 with round-to-nearest-even
__device__ __forceinline__ u32 packbf(float x, float y) {
    union { float f; u32 u; } ax, ay; ax.f = x; ay.f = y;
    u32 xr = (ax.u + 0x7fffu + ((ax.u >> 16) & 1u)) >> 16;
    u32 yr = (ay.u + 0x7fffu + ((ay.u >> 16) & 1u)) >> 16;
    return xr | (yr << 16);
}

__device__ __forceinline__ void addrow(float* acc, const uint4 v) {
    acc[0] += bflo(v.x); acc[1] += bfhi(v.x);
    acc[2] += bflo(v.y); acc[3] += bfhi(v.y);
    acc[4] += bflo(v.z); acc[5] += bfhi(v.z);
    acc[6] += bflo(v.w); acc[7] += bfhi(v.w);
}

// ---------------- CSR build (atomic-free counting sort) ----------------

__global__ __launch_bounds__(256) void chunkhist_kernel(const int* __restrict__ dst,
                                                        int* __restrict__ hist,
                                                        int n, int E, int chunk) {
    __shared__ int bins[MAXN];
    int tid = threadIdx.x;
    for (int i = tid; i < n; i += 256) bins[i] = 0;
    __syncthreads();
    int e0 = blockIdx.x * chunk;
    int e1 = min(e0 + chunk, E);
    for (int e = e0 + tid; e < e1; e += 256) atomicAdd(&bins[dst[e]], 1);
    __syncthreads();
    int* out = hist + (size_t)blockIdx.x * n;
    for (int i = tid; i < n; i += 256) out[i] = bins[i];
}

__global__ __launch_bounds__(256) void chunkscan_kernel(const int* __restrict__ hist,
                                                        int* __restrict__ chunkpref,
                                                        int* __restrict__ counts, int n) {
    int bin = blockIdx.x * 256 + threadIdx.x;
    if (bin >= n) return;
    const int* hp = hist + bin;
    int* cp = chunkpref + bin;
    int run = 0;
#pragma unroll 32
    for (int b = 0; b < CHUNKS; b++) {
        int v = hp[(size_t)b * n];
        cp[(size_t)b * n] = run;
        run += v;
    }
    counts[bin] = run;
}

__global__ __launch_bounds__(1024) void scan_kernel(const int* __restrict__ counts,
                                                    int* __restrict__ prowptr, int n) {
    __shared__ int sums[1024];
    const int CH = 16;
    int t = threadIdx.x;
    int base = t * CH;
    int local[CH];
    int s = 0;
#pragma unroll
    for (int i = 0; i < CH; i++) {
        int idx = base + i;
        local[i] = s;
        if (idx < n) s += (counts[idx] + 15) & ~15;
    }
    sums[t] = s;
    __syncthreads();
    for (int off = 1; off < 1024; off <<= 1) {
        int v = (t >= off) ? sums[t - off] : 0;
        __syncthreads();
        sums[t] += v;
        __syncthreads();
    }
    int prev = (t > 0) ? sums[t - 1] : 0;
#pragma unroll
    for (int i = 0; i < CH; i++) {
        int idx = base + i;
        if (idx < n) prowptr[idx] = prev + local[i];
    }
    if (t == 1023) prowptr[n] = sums[1023];
}

__global__ __launch_bounds__(256) void scatter_kernel(const int* __restrict__ src,
                                                      const int* __restrict__ dst,
                                                      const int* __restrict__ prowptr,
                                                      const int* __restrict__ chunkpref,
                                                      int* __restrict__ srcsorted,
                                                      int n, int E, int chunk) {
    __shared__ int cur[MAXN];
    int tid = threadIdx.x;
    const int* cp = chunkpref + (size_t)blockIdx.x * n;
    for (int i = tid; i < n; i += 256) cur[i] = prowptr[i] + cp[i];
    __syncthreads();
    int e0 = blockIdx.x * chunk;
    int e1 = min(e0 + chunk, E);
    for (int e = e0 + tid; e < e1; e += 256) {
        int d = dst[e];
        int pos = atomicAdd(&cur[d], 1);
        srcsorted[pos] = src[e];
    }
}

// ---------------- cooperative mega kernel ----------------
// Prologue: cvt x->bf16 (+zero dummy row n), pad srcsorted, zero gstats.
// Then 4 x {ab-preamble from prev stats | GIN gather (full-row uint4 loads,
// ILP x2) | per-block register stats -> one atomic flush} with grid.sync()
// between layers; epilogue applies layer-3 BN affine to fp32 out.
__global__ __launch_bounds__(256, 4) void mega_kernel(
    const float* __restrict__ x, u16* __restrict__ hbx,
    u16* __restrict__ hb0, u16* __restrict__ hb1,
    const int* __restrict__ prowptr, const int* __restrict__ counts,
    int* __restrict__ srcs, float* __restrict__ gstats,
    const float* __restrict__ gamma, const float* __restrict__ beta,
    float* __restrict__ out, int n, int total4, float inv_n) {
    cg::grid_group grid = cg::this_grid();
    __shared__ float ab_s[2 * DIM];
    __shared__ float part[2][DIM];
    __shared__ float ls[4][DIM];
    __shared__ float lq[4][DIM];
    int tid = threadIdx.x;
    int gsize = gridDim.x * 256;
    int gidx0 = blockIdx.x * 256 + tid;
    int wid = tid >> 6;
    int lane = tid & 63;
    int grp = lane >> 4;   // 0..3: edge-slot
    int sub = lane & 15;   // 16 lanes x uint4 = 256B = one bf16 row

    // ---- prologue ----
    for (int i = gidx0; i < total4; i += gsize) {
        float4 v = ((const float4*)x)[i];
        uint2 w;
        w.x = packbf(v.x, v.y);
        w.y = packbf(v.z, v.w);
        *(uint2*)(hbx + (size_t)i * 4) = w;
    }
    if (gidx0 < 96) {  // zero dummy row n of all 3 tables
        u16* t = (gidx0 < 32) ? hbx : ((gidx0 < 64) ? hb0 : hb1);
        uint2 z; z.x = 0; z.y = 0;
        *(uint2*)(t + (size_t)n * DIM + (gidx0 & 31) * 4) = z;
    }
    for (int i = gidx0; i < n; i += gsize) {  // pad-fill
        int pstart = prowptr[i];
        int c = counts[i];
        int p = (c + 15) & ~15;
        for (int k = c; k < p; k++) srcs[pstart + k] = n;  // dummy -> zero row
    }
    for (int i = gidx0; i < 4 * SPL; i += gsize) gstats[i] = 0.f;
    grid.sync();

    // ---- 4 layers ----
    const u16* hin = hbx;
    u16* houts[4] = {hb0, hb1, hb0, hb1};
    for (int l = 0; l < 4; l++) {
        u16* hout = houts[l];
        float* st_out = gstats + l * SPL;
        if (l > 0) {
            const float* st_in = gstats + (l - 1) * SPL;
            int c = tid & 127;
            int which = tid >> 7;
            const float* basep = st_in + which * NSLICE * DIM + c;
            float acc = 0.f;
#pragma unroll
            for (int k = 0; k < NSLICE; k++) acc += basep[k * DIM];
            part[which][c] = acc;
            __syncthreads();
            if (tid < DIM) {
                float mu = part[0][tid] * inv_n;
                float var = part[1][tid] * inv_n - mu * mu;
                float av = gamma[(l - 1) * DIM + tid] * rsqrtf(var + BN_EPS_F);
                ab_s[tid] = av;
                ab_s[DIM + tid] = beta[(l - 1) * DIM + tid] - mu * av;
            }
            __syncthreads();
        }

        float sacc[8], qacc[8];
#pragma unroll
        for (int k = 0; k < 8; k++) { sacc[k] = 0.f; qacc[k] = 0.f; }

        for (int node0 = blockIdx.x * 4; node0 < n; node0 += gridDim.x * 4) {
            int node = node0 + wid;
            if (node >= n) continue;
            int start = prowptr[node];
            int pend = prowptr[node + 1];
            int deg = counts[node];
            const u16* hsub = hin + sub * 8;
            float acc[8];
#pragma unroll
            for (int k = 0; k < 8; k++) acc[k] = 0.f;

            int eb = start;
            for (; eb + 32 <= pend; eb += 32) {
                int e0 = eb + grp * 4;
                int s0 = srcs[e0 + 0], s1 = srcs[e0 + 1];
                int s2 = srcs[e0 + 2], s3 = srcs[e0 + 3];
                int s4 = srcs[e0 + 16], s5 = srcs[e0 + 17];
                int s6 = srcs[e0 + 18], s7 = srcs[e0 + 19];
                uint4 v0 = *(const uint4*)(hsub + (size_t)s0 * DIM);
                uint4 v1 = *(const uint4*)(hsub + (size_t)s1 * DIM);
                uint4 v2 = *(const uint4*)(hsub + (size_t)s2 * DIM);
                uint4 v3 = *(const uint4*)(hsub + (size_t)s3 * DIM);
                uint4 v4 = *(const uint4*)(hsub + (size_t)s4 * DIM);
                uint4 v5 = *(const uint4*)(hsub + (size_t)s5 * DIM);
                uint4 v6 = *(const uint4*)(hsub + (size_t)s6 * DIM);
                uint4 v7 = *(const uint4*)(hsub + (size_t)s7 * DIM);
                addrow(acc, v0); addrow(acc, v1);
                addrow(acc, v2); addrow(acc, v3);
                addrow(acc, v4); addrow(acc, v5);
                addrow(acc, v6); addrow(acc, v7);
            }
            if (eb < pend) {  // one 16-edge tile remains
                int e0 = eb + grp * 4;
                int s0 = srcs[e0 + 0], s1 = srcs[e0 + 1];
                int s2 = srcs[e0 + 2], s3 = srcs[e0 + 3];
                uint4 v0 = *(const uint4*)(hsub + (size_t)s0 * DIM);
                uint4 v1 = *(const uint4*)(hsub + (size_t)s1 * DIM);
                uint4 v2 = *(const uint4*)(hsub + (size_t)s2 * DIM);
                uint4 v3 = *(const uint4*)(hsub + (size_t)s3 * DIM);
                addrow(acc, v0); addrow(acc, v1);
                addrow(acc, v2); addrow(acc, v3);
            }
#pragma unroll
            for (int k = 0; k < 8; k++) {
                acc[k] += __shfl_xor(acc[k], 16);
                acc[k] += __shfl_xor(acc[k], 32);
            }

            uint4 sv = *(const uint4*)(hin + (size_t)node * DIM + sub * 8);
            float self[8] = {bflo(sv.x), bfhi(sv.x), bflo(sv.y), bfhi(sv.y),
                             bflo(sv.z), bfhi(sv.z), bflo(sv.w), bfhi(sv.w)};
            float degp1 = 1.0f + (float)deg;

            float o[8];
            if (l > 0) {
                float4 a0 = *(const float4*)(ab_s + sub * 8);
                float4 a1 = *(const float4*)(ab_s + sub * 8 + 4);
                float4 b0 = *(const float4*)(ab_s + DIM + sub * 8);
                float4 b1 = *(const float4*)(ab_s + DIM + sub * 8 + 4);
                o[0] = a0.x * (self[0] + acc[0]) + degp1 * b0.x;
                o[1] = a0.y * (self[1] + acc[1]) + degp1 * b0.y;
                o[2] = a0.z * (self[2] + acc[2]) + degp1 * b0.z;
                o[3] = a0.w * (self[3] + acc[3]) + degp1 * b0.w;
                o[4] = a1.x * (self[4] + acc[4]) + degp1 * b1.x;
                o[5] = a1.y * (self[5] + acc[5]) + degp1 * b1.y;
                o[6] = a1.z * (self[6] + acc[6]) + degp1 * b1.z;
                o[7] = a1.w * (self[7] + acc[7]) + degp1 * b1.w;
            } else {
#pragma unroll
                for (int k = 0; k < 8; k++) o[k] = self[k] + acc[k];
            }
            u32 w0 = packbf(o[0], o[1]);
            u32 w1 = packbf(o[2], o[3]);
            u32 w2 = packbf(o[4], o[5]);
            u32 w3 = packbf(o[6], o[7]);
            if (grp == 0) {
                uint4 wv; wv.x = w0; wv.y = w1; wv.z = w2; wv.w = w3;
                *(uint4*)(hout + (size_t)node * DIM + sub * 8) = wv;
            }
            float rr[8] = {bflo(w0), bfhi(w0), bflo(w1), bfhi(w1),
                           bflo(w2), bfhi(w2), bflo(w3), bfhi(w3)};
#pragma unroll
            for (int k = 0; k < 8; k++) {
                sacc[k] += rr[k];
                qacc[k] += rr[k] * rr[k];
            }
        }

        // per-layer stats flush (grp 0 registers hold valid per-node sums)
        __syncthreads();
        if (grp == 0) {
#pragma unroll
            for (int k = 0; k < 8; k++) {
                ls[wid][sub * 8 + k] = sacc[k];
                lq[wid][sub * 8 + k] = qacc[k];
            }
        }
        __syncthreads();
        int slice = (blockIdx.x & (NSLICE - 1)) * DIM;
        int c2 = tid & 127;
        int which2 = tid >> 7;
        float sflush = which2 ? ((lq[0][c2] + lq[1][c2]) + (lq[2][c2] + lq[3][c2]))
                              : ((ls[0][c2] + ls[1][c2]) + (ls[2][c2] + ls[3][c2]));
        atomicAdd(&st_out[which2 * NSLICE * DIM + slice + c2], sflush);
        grid.sync();
        hin = hout;
    }

    // ---- epilogue: apply layer-3 BN affine ----
    {
        const float* st_in = gstats + 3 * SPL;
        int c = tid & 127;
        int which = tid >> 7;
        const float* basep = st_in + which * NSLICE * DIM + c;
        float acc = 0.f;
#pragma unroll
        for (int k = 0; k < NSLICE; k++) acc += basep[k * DIM];
        part[which][c] = acc;
        __syncthreads();
        if (tid < DIM) {
            float mu = part[0][tid] * inv_n;
            float var = part[1][tid] * inv_n - mu * mu;
            float av = gamma[3 * DIM + tid] * rsqrtf(var + BN_EPS_F);
            ab_s[tid] = av;
            ab_s[DIM + tid] = beta[3 * DIM + tid] - mu * av;
        }
        __syncthreads();
        const u16* hb = hin;  // = hb1 after layer 3
        for (int i = gidx0; i < total4; i += gsize) {
            int quad = i & 31;
            uint2 w = *(const uint2*)(hb + (size_t)i * 4);
            const float4 a = *(const float4*)(ab_s + quad * 4);
            const float4 b = *(const float4*)(ab_s + DIM + quad * 4);
            float4 r;
            r.x = a.x * bflo(w.x) + b.x;
            r.y = a.y * bfhi(w.x) + b.y;
            r.z = a.z * bflo(w.y) + b.z;
            r.w = a.w * bfhi(w.y) + b.w;
            ((float4*)out)[i] = r;
        }
    }
}

extern "C" void kernel_launch(void* const* d_in, const int* in_sizes, int n_in,
                              void* d_out, int out_size, void* d_ws, size_t ws_size,
                              hipStream_t stream) {
    const float* x = (const float*)d_in[0];
    const float* gamma = (const float*)d_in[1];
    const float* beta = (const float*)d_in[2];
    const int* src = (const int*)d_in[3];
    const int* dst = (const int*)d_in[4];
    float* out = (float*)d_out;

    const int n = in_sizes[0] / DIM;   // 10000
    const int E = in_sizes[3];         // 640000

    char* ws = (char*)d_ws;
    auto alloc = [&](size_t bytes) -> char* {
        char* p = ws;
        ws += (bytes + 255) / 256 * 256;
        return p;
    };
    int* prowptr = (int*)alloc((size_t)(n + 1) * 4);
    int* counts = (int*)alloc((size_t)n * 4);
    float* gstats = (float*)alloc((size_t)4 * SPL * 4);
    int* hist = (int*)alloc((size_t)CHUNKS * n * 4);
    int* chunkpref = (int*)alloc((size_t)CHUNKS * n * 4);
    int* srcsorted = (int*)alloc((size_t)(E + 16 * n) * 4);       // padded
    u16* hbx = (u16*)alloc((size_t)(n + 1) * DIM * 2);
    u16* hb0 = (u16*)alloc((size_t)(n + 1) * DIM * 2);
    u16* hb1 = (u16*)alloc((size_t)(n + 1) * DIM * 2);

    const int chunk = (E + CHUNKS - 1) / CHUNKS;
    const int total4 = n * DIM / 4;
    const float inv_n = 1.0f / n;

    chunkhist_kernel<<<CHUNKS, 256, 0, stream>>>(dst, hist, n, E, chunk);
    chunkscan_kernel<<<(n + 255) / 256, 256, 0, stream>>>(hist, chunkpref, counts, n);
    scan_kernel<<<1, 1024, 0, stream>>>(counts, prowptr, n);
    scatter_kernel<<<CHUNKS, 256, 0, stream>>>(src, dst, prowptr, chunkpref, srcsorted,
                                               n, E, chunk);

    // cooperative mega kernel: size grid to exact co-residency
    hipDeviceProp_t prop;
    hipGetDeviceProperties(&prop, 0);
    int nbPerCU = 0;
    hipOccupancyMaxActiveBlocksPerMultiprocessor(&nbPerCU, mega_kernel, 256, 0);
    if (nbPerCU < 1) nbPerCU = 1;
    long long gb = (long long)nbPerCU * prop.multiProcessorCount;
    if (gb > 2048) gb = 2048;
    int GB = (int)gb;

    int n_ = n, total4_ = total4;
    float inv_n_ = inv_n;
    void* kargs[] = {(void*)&x, (void*)&hbx, (void*)&hb0, (void*)&hb1,
                     (void*)&prowptr, (void*)&counts, (void*)&srcsorted,
                     (void*)&gstats, (void*)&gamma, (void*)&beta,
                     (void*)&out, (void*)&n_, (void*)&total4_, (void*)&inv_n_};
    hipLaunchCooperativeKernel((void*)mega_kernel, dim3(GB), dim3(256), kargs, 0, stream);
}

// Round 12
// 181.532 us; speedup vs baseline: 2.7338x; 2.7338x over previous
//
#include <hip/hip_runtime.h>

#define DIM 128
#define BN_EPS_F 1e-5f
#define NSLICE 16   // stat slices: spreads atomic contention; preamble reduces them
#define MAXN 10240  // LDS histogram capacity (n = 10000)
#define CHUNKS 128  // edge chunks == blocks in chunkhist/scatter

typedef unsigned int u32;
typedef unsigned short u16;

__device__ __forceinline__ float bflo(u32 w) {
    union { u32 u; float f; } c; c.u = w << 16; return c.f;
}
__device__ __forceinline__ float bfhi(u32 w) {
    union { u32 u; float f; } c; c.u = w & 0xffff0000u; return c.f;
}
// pack two floats to bf16x2 with round-to-nearest-even
__device__ __forceinline__ u32 packbf(float x, float y) {
    union { float f; u32 u; } ax, ay; ax.f = x; ay.f = y;
    u32 xr = (ax.u + 0x7fffu + ((ax.u >> 16) & 1u)) >> 16;
    u32 yr = (ay.u + 0x7fffu + ((ay.u >> 16) & 1u)) >> 16;
    return xr | (yr << 16);
}

// ---------------- CSR build (atomic-free counting sort) ----------------

// A: per-chunk private LDS histogram -> hist[chunk][bin]
__global__ __launch_bounds__(256) void chunkhist_kernel(const int* __restrict__ dst,
                                                        int* __restrict__ hist,
                                                        int n, int E, int chunk) {
    __shared__ int bins[MAXN];
    int tid = threadIdx.x;
    for (int i = tid; i < n; i += 256) bins[i] = 0;
    __syncthreads();
    int e0 = blockIdx.x * chunk;
    int e1 = min(e0 + chunk, E);
    for (int e = e0 + tid; e < e1; e += 256) atomicAdd(&bins[dst[e]], 1);
    __syncthreads();
    int* out = hist + (size_t)blockIdx.x * n;
    for (int i = tid; i < n; i += 256) out[i] = bins[i];
}

// B1: per-bin exclusive prefix over chunks; counts[bin] = total degree
__global__ __launch_bounds__(256) void chunkscan_kernel(const int* __restrict__ hist,
                                                        int* __restrict__ chunkpref,
                                                        int* __restrict__ counts, int n) {
    int bin = blockIdx.x * 256 + threadIdx.x;
    if (bin >= n) return;
    const int* hp = hist + bin;
    int* cp = chunkpref + bin;
    int run = 0;
#pragma unroll 32
    for (int b = 0; b < CHUNKS; b++) {
        int v = hp[(size_t)b * n];
        cp[(size_t)b * n] = run;
        run += v;
    }
    counts[bin] = run;
}

// B2: exclusive scan of 16-PADDED counts -> prowptr (scan only)
__global__ __launch_bounds__(1024) void scan_kernel(const int* __restrict__ counts,
                                                    int* __restrict__ prowptr, int n) {
    __shared__ int sums[1024];
    const int CH = 16;
    int t = threadIdx.x;
    int base = t * CH;
    int local[CH];
    int s = 0;
#pragma unroll
    for (int i = 0; i < CH; i++) {
        int idx = base + i;
        local[i] = s;
        if (idx < n) s += (counts[idx] + 15) & ~15;
    }
    sums[t] = s;
    __syncthreads();
    for (int off = 1; off < 1024; off <<= 1) {
        int v = (t >= off) ? sums[t - off] : 0;
        __syncthreads();
        sums[t] += v;
        __syncthreads();
    }
    int prev = (t > 0) ? sums[t - 1] : 0;
#pragma unroll
    for (int i = 0; i < CH; i++) {
        int idx = base + i;
        if (idx < n) prowptr[idx] = prev + local[i];
    }
    if (t == 1023) prowptr[n] = sums[1023];
}

// B3: misc fused kernel — cvt x->bf16 (+zero dummy rows), zero gstats
__global__ __launch_bounds__(256) void misc_kernel(const float* __restrict__ x,
                                                   u16* __restrict__ xb,
                                                   u16* __restrict__ r0,
                                                   u16* __restrict__ r1,
                                                   float* __restrict__ gstats,
                                                   int total4, int n,
                                                   int nb_cvt, int gtotal) {
    int bid = blockIdx.x;
    int tid = threadIdx.x;
    if (bid < nb_cvt) {
        int i = bid * 256 + tid;
        if (i < total4) {
            float4 v = ((const float4*)x)[i];
            uint2 w;
            w.x = packbf(v.x, v.y);
            w.y = packbf(v.z, v.w);
            *(uint2*)(xb + (size_t)i * 4) = w;
        } else {
            int j = i - total4;
            if (j < 96) {
                u16* t = (j < 32) ? xb : ((j < 64) ? r0 : r1);
                uint2 z; z.x = 0; z.y = 0;
                *(uint2*)(t + (size_t)n * DIM + (j & 31) * 4) = z;
            }
        }
    } else {
        int i = (bid - nb_cvt) * 256 + tid;
        if (i < gtotal) gstats[i] = 0.f;
    }
}

// C: scatter via LDS-ranked positions (no global atomics) + pad-fill of this
// block's node slice (pad slots are disjoint from all scatter writes)
__global__ __launch_bounds__(256) void scatter_kernel(const int* __restrict__ src,
                                                      const int* __restrict__ dst,
                                                      const int* __restrict__ prowptr,
                                                      const int* __restrict__ chunkpref,
                                                      const int* __restrict__ counts,
                                                      int* __restrict__ srcsorted,
                                                      int n, int E, int chunk, int nslice) {
    __shared__ int cur[MAXN];
    int tid = threadIdx.x;
    const int* cp = chunkpref + (size_t)blockIdx.x * n;
    for (int i = tid; i < n; i += 256) cur[i] = prowptr[i] + cp[i];
    __syncthreads();
    // pad-fill this block's node slice
    int i0 = blockIdx.x * nslice;
    int i1 = min(i0 + nslice, n);
    for (int i = i0 + tid; i < i1; i += 256) {
        int pstart = prowptr[i];
        int c = counts[i];
        int p = (c + 15) & ~15;
        for (int k = c; k < p; k++) srcsorted[pstart + k] = n;  // dummy -> zero row
    }
    int e0 = blockIdx.x * chunk;
    int e1 = min(e0 + chunk, E);
    for (int e = e0 + tid; e < e1; e += 256) {
        int d = dst[e];
        int pos = atomicAdd(&cur[d], 1);
        srcsorted[pos] = src[e];
    }
}

// ---------------- fused affine(prev-BN) + GIN aggregate + stats ----------------
// Preamble (USE_AB): every block reduces the PREVIOUS layer's sliced stats and
// computes a,b into LDS (kernel boundary = free device-wide sync; no fences).
// Body: one 64-lane wave per node; lane = grp(4) x sub(16). Each 16-lane group
// reads a FULL 256B bf16 row with one uint4 load. Unroll x2 -> 8 independent
// {srcs -> row} chains in flight per wave. Edge lists 16-padded (dummy node n,
// zero row) -> no scalar tail.
// Epilogue: block-reduce rounded outputs, fp32 atomics into THIS layer's slice.
template <int USE_AB>
__global__ __launch_bounds__(256) void gather_kernel(
    const u16* __restrict__ hin, u16* __restrict__ hout,
    const int* __restrict__ prowptr, const int* __restrict__ counts,
    const int* __restrict__ srcs,
    const float* __restrict__ stats_in, float* __restrict__ stats_out,
    const float* __restrict__ gamma, const float* __restrict__ beta,
    int n, float inv_n) {
    __shared__ float ab_s[2 * DIM];
    __shared__ float part[2][DIM];
    __shared__ float ls[4][DIM];
    __shared__ float lq[4][DIM];
    int tid = threadIdx.x;
    int wid = tid >> 6;
    int node = blockIdx.x * 4 + wid;
    int lane = tid & 63;
    int grp = lane >> 4;   // 0..3: which edge-slot
    int sub = lane & 15;   // 16 lanes x uint4 = 256B = one bf16 row

    if (USE_AB) {
        int c = tid & 127;
        int which = tid >> 7;  // 0 = sums, 1 = squares
        const float* basep = stats_in + which * NSLICE * DIM + c;
        float acc = 0.f;
#pragma unroll
        for (int k = 0; k < NSLICE; k++) acc += basep[k * DIM];
        part[which][c] = acc;
        __syncthreads();
        if (tid < DIM) {
            float mu = part[0][tid] * inv_n;
            float var = part[1][tid] * inv_n - mu * mu;
            float av = gamma[tid] * rsqrtf(var + BN_EPS_F);
            ab_s[tid] = av;
            ab_s[DIM + tid] = beta[tid] - mu * av;
        }
        __syncthreads();
    }

    float r[8];
#pragma unroll
    for (int k = 0; k < 8; k++) r[k] = 0.f;

    if (node < n) {
        int start = prowptr[node];
        int pend = prowptr[node + 1];
        int deg = counts[node];
        const u16* hsub = hin + sub * 8;
        float acc[8];
#pragma unroll
        for (int k = 0; k < 8; k++) acc[k] = 0.f;

        int eb = start;
        for (; eb + 32 <= pend; eb += 32) {
            int e0 = eb + grp * 4;
            int s0 = srcs[e0 + 0];
            int s1 = srcs[e0 + 1];
            int s2 = srcs[e0 + 2];
            int s3 = srcs[e0 + 3];
            int s4 = srcs[e0 + 16];
            int s5 = srcs[e0 + 17];
            int s6 = srcs[e0 + 18];
            int s7 = srcs[e0 + 19];
            uint4 v0 = *(const uint4*)(hsub + (size_t)s0 * DIM);
            uint4 v1 = *(const uint4*)(hsub + (size_t)s1 * DIM);
            uint4 v2 = *(const uint4*)(hsub + (size_t)s2 * DIM);
            uint4 v3 = *(const uint4*)(hsub + (size_t)s3 * DIM);
            uint4 v4 = *(const uint4*)(hsub + (size_t)s4 * DIM);
            uint4 v5 = *(const uint4*)(hsub + (size_t)s5 * DIM);
            uint4 v6 = *(const uint4*)(hsub + (size_t)s6 * DIM);
            uint4 v7 = *(const uint4*)(hsub + (size_t)s7 * DIM);
            acc[0] += ((bflo(v0.x) + bflo(v1.x)) + (bflo(v2.x) + bflo(v3.x))) +
                      ((bflo(v4.x) + bflo(v5.x)) + (bflo(v6.x) + bflo(v7.x)));
            acc[1] += ((bfhi(v0.x) + bfhi(v1.x)) + (bfhi(v2.x) + bfhi(v3.x))) +
                      ((bfhi(v4.x) + bfhi(v5.x)) + (bfhi(v6.x) + bfhi(v7.x)));
            acc[2] += ((bflo(v0.y) + bflo(v1.y)) + (bflo(v2.y) + bflo(v3.y))) +
                      ((bflo(v4.y) + bflo(v5.y)) + (bflo(v6.y) + bflo(v7.y)));
            acc[3] += ((bfhi(v0.y) + bfhi(v1.y)) + (bfhi(v2.y) + bfhi(v3.y))) +
                      ((bfhi(v4.y) + bfhi(v5.y)) + (bfhi(v6.y) + bfhi(v7.y)));
            acc[4] += ((bflo(v0.z) + bflo(v1.z)) + (bflo(v2.z) + bflo(v3.z))) +
                      ((bflo(v4.z) + bflo(v5.z)) + (bflo(v6.z) + bflo(v7.z)));
            acc[5] += ((bfhi(v0.z) + bfhi(v1.z)) + (bfhi(v2.z) + bfhi(v3.z))) +
                      ((bfhi(v4.z) + bfhi(v5.z)) + (bfhi(v6.z) + bfhi(v7.z)));
            acc[6] += ((bflo(v0.w) + bflo(v1.w)) + (bflo(v2.w) + bflo(v3.w))) +
                      ((bflo(v4.w) + bflo(v5.w)) + (bflo(v6.w) + bflo(v7.w)));
            acc[7] += ((bfhi(v0.w) + bfhi(v1.w)) + (bfhi(v2.w) + bfhi(v3.w))) +
                      ((bfhi(v4.w) + bfhi(v5.w)) + (bfhi(v6.w) + bfhi(v7.w)));
        }
        if (eb < pend) {  // exactly one 16-edge block remains
            int e0 = eb + grp * 4;
            int s0 = srcs[e0 + 0];
            int s1 = srcs[e0 + 1];
            int s2 = srcs[e0 + 2];
            int s3 = srcs[e0 + 3];
            uint4 v0 = *(const uint4*)(hsub + (size_t)s0 * DIM);
            uint4 v1 = *(const uint4*)(hsub + (size_t)s1 * DIM);
            uint4 v2 = *(const uint4*)(hsub + (size_t)s2 * DIM);
            uint4 v3 = *(const uint4*)(hsub + (size_t)s3 * DIM);
            acc[0] += (bflo(v0.x) + bflo(v1.x)) + (bflo(v2.x) + bflo(v3.x));
            acc[1] += (bfhi(v0.x) + bfhi(v1.x)) + (bfhi(v2.x) + bfhi(v3.x));
            acc[2] += (bflo(v0.y) + bflo(v1.y)) + (bflo(v2.y) + bflo(v3.y));
            acc[3] += (bfhi(v0.y) + bfhi(v1.y)) + (bfhi(v2.y) + bfhi(v3.y));
            acc[4] += (bflo(v0.z) + bflo(v1.z)) + (bflo(v2.z) + bflo(v3.z));
            acc[5] += (bfhi(v0.z) + bfhi(v1.z)) + (bfhi(v2.z) + bfhi(v3.z));
            acc[6] += (bflo(v0.w) + bflo(v1.w)) + (bflo(v2.w) + bflo(v3.w));
            acc[7] += (bfhi(v0.w) + bfhi(v1.w)) + (bfhi(v2.w) + bfhi(v3.w));
        }
        // reduce the 4 groups: lanes with same sub end up with the full sum
#pragma unroll
        for (int k = 0; k < 8; k++) {
            acc[k] += __shfl_xor(acc[k], 16);
            acc[k] += __shfl_xor(acc[k], 32);
        }

        uint4 sv = *(const uint4*)(hin + (size_t)node * DIM + sub * 8);
        float self[8] = {bflo(sv.x), bfhi(sv.x), bflo(sv.y), bfhi(sv.y),
                         bflo(sv.z), bfhi(sv.z), bflo(sv.w), bfhi(sv.w)};
        float degp1 = 1.0f + (float)deg;

        float av[8], bv[8];
        if (USE_AB) {
            float4 a0 = *(const float4*)(ab_s + sub * 8);
            float4 a1 = *(const float4*)(ab_s + sub * 8 + 4);
            float4 b0 = *(const float4*)(ab_s + DIM + sub * 8);
            float4 b1 = *(const float4*)(ab_s + DIM + sub * 8 + 4);
            av[0] = a0.x; av[1] = a0.y; av[2] = a0.z; av[3] = a0.w;
            av[4] = a1.x; av[5] = a1.y; av[6] = a1.z; av[7] = a1.w;
            bv[0] = b0.x; bv[1] = b0.y; bv[2] = b0.z; bv[3] = b0.w;
            bv[4] = b1.x; bv[5] = b1.y; bv[6] = b1.z; bv[7] = b1.w;
        } else {
#pragma unroll
            for (int k = 0; k < 8; k++) { av[k] = 1.f; bv[k] = 0.f; }
        }

        float o[8];
#pragma unroll
        for (int k = 0; k < 8; k++) o[k] = av[k] * (self[k] + acc[k]) + degp1 * bv[k];
        u32 w0 = packbf(o[0], o[1]);
        u32 w1 = packbf(o[2], o[3]);
        u32 w2 = packbf(o[4], o[5]);
        u32 w3 = packbf(o[6], o[7]);
        if (grp == 0) {
            uint4 wv; wv.x = w0; wv.y = w1; wv.z = w2; wv.w = w3;
            *(uint4*)(hout + (size_t)node * DIM + sub * 8) = wv;
        }
        r[0] = bflo(w0); r[1] = bfhi(w0); r[2] = bflo(w1); r[3] = bfhi(w1);
        r[4] = bflo(w2); r[5] = bfhi(w2); r[6] = bflo(w3); r[7] = bfhi(w3);
    }

    // stats of rounded values (grp 0 holds the final r for its node; zeros if node>=n)
    if (grp == 0) {
#pragma unroll
        for (int k = 0; k < 8; k++) {
            ls[wid][sub * 8 + k] = r[k];
            lq[wid][sub * 8 + k] = r[k] * r[k];
        }
    }
    __syncthreads();
    int slice = (blockIdx.x & (NSLICE - 1)) * DIM;
    int c = tid & 127;
    int which = tid >> 7;
    float s = which ? ((lq[0][c] + lq[1][c]) + (lq[2][c] + lq[3][c]))
                    : ((ls[0][c] + ls[1][c]) + (ls[2][c] + ls[3][c]));
    atomicAdd(&stats_out[which * NSLICE * DIM + slice + c], s);
}

// ---------------- final affine apply (layer 3) ----------------
__global__ __launch_bounds__(256) void apply_kernel(const u16* __restrict__ hb,
                                                    const float* __restrict__ stats_in,
                                                    const float* __restrict__ gamma,
                                                    const float* __restrict__ beta,
                                                    float* __restrict__ out, int total4,
                                                    float inv_n) {
    __shared__ float ab_s[2 * DIM];
    __shared__ float part[2][DIM];
    int tid = threadIdx.x;
    {
        int c = tid & 127;
        int which = tid >> 7;
        const float* basep = stats_in + which * NSLICE * DIM + c;
        float acc = 0.f;
#pragma unroll
        for (int k = 0; k < NSLICE; k++) acc += basep[k * DIM];
        part[which][c] = acc;
        __syncthreads();
        if (tid < DIM) {
            float mu = part[0][tid] * inv_n;
            float var = part[1][tid] * inv_n - mu * mu;
            float av = gamma[tid] * rsqrtf(var + BN_EPS_F);
            ab_s[tid] = av;
            ab_s[DIM + tid] = beta[tid] - mu * av;
        }
        __syncthreads();
    }
    for (int i = blockIdx.x * blockDim.x + tid; i < total4; i += gridDim.x * blockDim.x) {
        int quad = i & 31;
        uint2 w = *(const uint2*)(hb + (size_t)i * 4);
        const float4 a = *(const float4*)(ab_s + quad * 4);
        const float4 b = *(const float4*)(ab_s + DIM + quad * 4);
        float4 r;
        r.x = a.x * bflo(w.x) + b.x;
        r.y = a.y * bfhi(w.x) + b.y;
        r.z = a.z * bflo(w.y) + b.z;
        r.w = a.w * bfhi(w.y) + b.w;
        ((float4*)out)[i] = r;
    }
}

extern "C" void kernel_launch(void* const* d_in, const int* in_sizes, int n_in,
                              void* d_out, int out_size, void* d_ws, size_t ws_size,
                              hipStream_t stream) {
    const float* x = (const float*)d_in[0];
    const float* gamma = (const float*)d_in[1];
    const float* beta = (const float*)d_in[2];
    const int* src = (const int*)d_in[3];
    const int* dst = (const int*)d_in[4];
    float* out = (float*)d_out;

    const int n = in_sizes[0] / DIM;   // 10000
    const int E = in_sizes[3];         // 640000

    char* ws = (char*)d_ws;
    auto alloc = [&](size_t bytes) -> char* {
        char* p = ws;
        ws += (bytes + 255) / 256 * 256;
        return p;
    };
    const int STATS_PER_LAYER = 2 * NSLICE * DIM;                 // sums + squares
    int* prowptr = (int*)alloc((size_t)(n + 1) * 4);
    int* counts = (int*)alloc((size_t)n * 4);
    float* gstats = (float*)alloc((size_t)4 * STATS_PER_LAYER * 4);
    int* hist = (int*)alloc((size_t)CHUNKS * n * 4);
    int* chunkpref = (int*)alloc((size_t)CHUNKS * n * 4);
    int* srcsorted = (int*)alloc((size_t)(E + 16 * n) * 4);       // padded
    u16* hbx = (u16*)alloc((size_t)(n + 1) * DIM * 2);
    u16* hb0 = (u16*)alloc((size_t)(n + 1) * DIM * 2);
    u16* hb1 = (u16*)alloc((size_t)(n + 1) * DIM * 2);

    const int chunk = (E + CHUNKS - 1) / CHUNKS;
    const int nslice = (n + CHUNKS - 1) / CHUNKS;
    const int total4 = n * DIM / 4;
    const int gtotal = 4 * STATS_PER_LAYER;
    const int NB_CVT = (total4 + 96 + 255) / 256;
    const int NB_GZ = (gtotal + 255) / 256;

    chunkhist_kernel<<<CHUNKS, 256, 0, stream>>>(dst, hist, n, E, chunk);
    chunkscan_kernel<<<(n + 255) / 256, 256, 0, stream>>>(hist, chunkpref, counts, n);
    scan_kernel<<<1, 1024, 0, stream>>>(counts, prowptr, n);
    misc_kernel<<<NB_CVT + NB_GZ, 256, 0, stream>>>(x, hbx, hb0, hb1, gstats,
                                                    total4, n, NB_CVT, gtotal);
    scatter_kernel<<<CHUNKS, 256, 0, stream>>>(src, dst, prowptr, chunkpref, counts,
                                               srcsorted, n, E, chunk, nslice);

    const int GB = (n + 3) / 4;  // one 64-lane wave per node
    const float inv_n = 1.0f / n;
    float* st0 = gstats + 0 * STATS_PER_LAYER;
    float* st1 = gstats + 1 * STATS_PER_LAYER;
    float* st2 = gstats + 2 * STATS_PER_LAYER;
    float* st3 = gstats + 3 * STATS_PER_LAYER;

    gather_kernel<0><<<GB, 256, 0, stream>>>(hbx, hb0, prowptr, counts, srcsorted,
                                             nullptr, st0, nullptr, nullptr, n, inv_n);
    gather_kernel<1><<<GB, 256, 0, stream>>>(hb0, hb1, prowptr, counts, srcsorted,
                                             st0, st1, gamma + 0 * DIM, beta + 0 * DIM,
                                             n, inv_n);
    gather_kernel<1><<<GB, 256, 0, stream>>>(hb1, hb0, prowptr, counts, srcsorted,
                                             st1, st2, gamma + 1 * DIM, beta + 1 * DIM,
                                             n, inv_n);
    gather_kernel<1><<<GB, 256, 0, stream>>>(hb0, hb1, prowptr, counts, srcsorted,
                                             st2, st3, gamma + 2 * DIM, beta + 2 * DIM,
                                             n, inv_n);
    apply_kernel<<<256, 256, 0, stream>>>(hb1, st3, gamma + 3 * DIM, beta + 3 * DIM, out,
                                          total4, inv_n);
}